// Round 2
// baseline (322.541 us; speedup 1.0000x reference)
//
#include <hip/hip_runtime.h>
#include <cstddef>

#define NND  65536
#define PP   1024
#define EE   16384
#define TJ   16
#define TI   32
#define EPSF 1e-6f

// ---------------- setup kernels ----------------

__global__ void patch_bounds_kernel(const int* __restrict__ batch, int* __restrict__ start) {
    int i = blockIdx.x * blockDim.x + threadIdx.x;
    if (i >= NND) return;
    int b  = batch[i];
    int bp = (i == 0) ? -1 : batch[i - 1];
    for (int p = bp + 1; p <= b; ++p) start[p] = i;
    if (i == NND - 1) {
        for (int p = b + 1; p <= PP; ++p) start[p] = NND;
    }
}

__global__ void edge_hist_kernel(const int* __restrict__ row, const int* __restrict__ col,
                                 const float* __restrict__ attr,
                                 float* __restrict__ deg, int* __restrict__ colcnt) {
    int e = blockIdx.x * blockDim.x + threadIdx.x;
    if (e >= EE) return;
    atomicAdd(&deg[row[e]], attr[e]);   // degree by ROW (for dinv)
    atomicAdd(&colcnt[col[e]], 1);      // CSR by COL
}

__global__ void scan_dinv_kernel(const int* __restrict__ colcnt, int* __restrict__ col_start,
                                 const float* __restrict__ deg, float* __restrict__ dinv) {
    __shared__ int s[PP];
    int t = threadIdx.x;
    s[t] = colcnt[t];
    float dg = deg[t];
    dinv[t] = (dg > 0.f) ? rsqrtf(fmaxf(dg, EPSF)) : 0.f;
    __syncthreads();
    for (int off = 1; off < PP; off <<= 1) {
        int v = (t >= off) ? s[t - off] : 0;
        __syncthreads();
        s[t] += v;
        __syncthreads();
    }
    col_start[t + 1] = s[t];
    if (t == 0) col_start[0] = 0;
}

__global__ void edge_scatter_kernel(const int* __restrict__ col, const int* __restrict__ col_start,
                                    int* __restrict__ colfill, int* __restrict__ edge_perm) {
    int e = blockIdx.x * blockDim.x + threadIdx.x;
    if (e >= EE) return;
    int c = col[e];
    int pos = col_start[c] + atomicAdd(&colfill[c], 1);
    edge_perm[pos] = e;
}

// ---------------- MLP building blocks (row-per-thread, 128 rows/block) ----------------

__device__ __forceinline__ void load_w(const float* __restrict__ W, const float* __restrict__ b,
                                       float* Ws, float* bs, int t) {
    const float4* w4 = (const float4*)W;
    float4* ws4 = (float4*)Ws;
    for (int i = t; i < 1024; i += 128) ws4[i] = w4[i];
    if (t < 64) bs[t] = b[t];
}

__device__ __forceinline__ void mlp_pass(const float (*xs)[65], const float* Ws, const float* bs,
                                         int t, float* acc) {
#pragma unroll
    for (int d = 0; d < 64; ++d) acc[d] = bs[d];
#pragma unroll 4
    for (int k = 0; k < 64; ++k) {
        float xv = xs[t][k];                  // bank (t+k)%32: conflict-free
#pragma unroll
        for (int d = 0; d < 64; ++d)          // Ws[k*64+d]: wave-uniform broadcast
            acc[d] = fmaf(xv, Ws[k * 64 + d], acc[d]);
    }
}

__device__ __forceinline__ void store_row(float* __restrict__ dst, const float* acc, bool relu) {
#pragma unroll
    for (int q = 0; q < 16; ++q) {
        float4 v = make_float4(acc[4*q], acc[4*q+1], acc[4*q+2], acc[4*q+3]);
        if (relu) { v.x=fmaxf(v.x,0.f); v.y=fmaxf(v.y,0.f); v.z=fmaxf(v.z,0.f); v.w=fmaxf(v.w,0.f); }
        ((float4*)dst)[q] = v;
    }
}

template <bool TWO, bool GATHER, bool RELU_OUT>
__global__ __launch_bounds__(128)
void mlp2_kernel(const float* __restrict__ in, const int* __restrict__ gmap,
                 const float* __restrict__ W1, const float* __restrict__ b1,
                 const float* __restrict__ W2, const float* __restrict__ b2,
                 float* __restrict__ out) {
    __shared__ float xs[128][65];
    __shared__ float Ws[4096];
    __shared__ float bs[64];
    __shared__ int gr[128];
    int t = threadIdx.x;
    int row0 = blockIdx.x * 128;
    if (GATHER) gr[t] = gmap[row0 + t];
    load_w(W1, b1, Ws, bs, t);
    __syncthreads();
    // cooperative x staging (coalesced)
    for (int idx = t; idx < 128 * 16; idx += 128) {
        int r = idx >> 4, q = idx & 15;
        int sr = GATHER ? gr[r] : (row0 + r);
        float4 v = ((const float4*)(in + (size_t)sr * 64))[q];
        float* xd = &xs[r][q * 4];
        xd[0] = v.x; xd[1] = v.y; xd[2] = v.z; xd[3] = v.w;
    }
    __syncthreads();
    float acc[64];
    mlp_pass(xs, Ws, bs, t, acc);
    if (TWO) {
#pragma unroll
        for (int d = 0; d < 64; ++d) xs[t][d] = fmaxf(acc[d], 0.f);  // own row only: race-free
        __syncthreads();
        load_w(W2, b2, Ws, bs, t);
        __syncthreads();
        mlp_pass(xs, Ws, bs, t, acc);
    }
    store_row(out + (size_t)(row0 + t) * 64, acc, RELU_OUT);
}

// fused Q-pre / K / V: one gather of h, 4 layers, W buffer reloaded per layer
__global__ __launch_bounds__(128)
void qkv_kernel(const float* __restrict__ h, const int* __restrict__ gmap,
                const float* __restrict__ Wk, const float* __restrict__ bk,
                const float* __restrict__ Wv, const float* __restrict__ bv,
                const float* __restrict__ Wp1, const float* __restrict__ bp1,
                const float* __restrict__ Wp2, const float* __restrict__ bp2,
                float* __restrict__ Kout, float* __restrict__ Vout, float* __restrict__ Qout) {
    __shared__ float xs[128][65];
    __shared__ float Ws[4096];
    __shared__ float bs[64];
    __shared__ int gr[128];
    int t = threadIdx.x;
    int row0 = blockIdx.x * 128;
    gr[t] = gmap[row0 + t];
    load_w(Wk, bk, Ws, bs, t);
    __syncthreads();
    for (int idx = t; idx < 128 * 16; idx += 128) {
        int r = idx >> 4, q = idx & 15;
        float4 v = ((const float4*)(h + (size_t)gr[r] * 64))[q];
        float* xd = &xs[r][q * 4];
        xd[0] = v.x; xd[1] = v.y; xd[2] = v.z; xd[3] = v.w;
    }
    __syncthreads();
    float acc[64];
    mlp_pass(xs, Ws, bs, t, acc);                       // K = hs@Wk+bk
    store_row(Kout + (size_t)(row0 + t) * 64, acc, false);
    __syncthreads();
    load_w(Wv, bv, Ws, bs, t);
    __syncthreads();
    mlp_pass(xs, Ws, bs, t, acc);                       // V = hs@Wv+bv
    store_row(Vout + (size_t)(row0 + t) * 64, acc, false);
    __syncthreads();
    load_w(Wp1, bp1, Ws, bs, t);
    __syncthreads();
    mlp_pass(xs, Ws, bs, t, acc);                       // t1 = relu(hs@Wp1+bp1)
#pragma unroll
    for (int d = 0; d < 64; ++d) xs[t][d] = fmaxf(acc[d], 0.f);
    __syncthreads();
    load_w(Wp2, bp2, Ws, bs, t);
    __syncthreads();
    mlp_pass(xs, Ws, bs, t, acc);                       // Q = t1@Wp2+bp2
    store_row(Qout + (size_t)(row0 + t) * 64, acc, false);
}

// ---------------- per-patch reductions ----------------

__global__ __launch_bounds__(256)
void patch_reduce_kernel(const float* __restrict__ Qn, const float* __restrict__ K,
                         const int* __restrict__ start,
                         float* __restrict__ Qs_raw, float* __restrict__ Ksk) {
    __shared__ float qred[4][64], kred[4][64];
    int p = blockIdx.x, t = threadIdx.x;
    int d = t & 63, s = t >> 6;
    int i0 = start[p], i1 = start[p + 1];
    float qa = 0.f, ka = 0.f;
    for (int i = i0 + s; i < i1; i += 4) {
        qa += Qn[(size_t)i * 64 + d];
        ka += K[(size_t)i * 64 + d];
    }
    qred[s][d] = qa; kred[s][d] = ka;
    __syncthreads();
    if (s == 0) {
        float q = qred[0][d] + qred[1][d] + qred[2][d] + qred[3][d];
        float k = kred[0][d] + kred[1][d] + kred[2][d] + kred[3][d];
        Qs_raw[(size_t)p * 64 + d] = q;
        int cnt = i1 - i0;
        Ksk[(size_t)p * 64 + d] = fmaxf(k / (float)max(cnt, 1), 0.f);
    }
}

// ---------------- col-grouped kernelized attention (M never materialized) ----------------
// block c: for targets {c (coeff 1)} ∪ {row_e : col_e==c (coeff a_e)}:
//   num[p] += coeff * Σ_{i∈c} (Qk_p·relu(K_i)) V_i ;  Kagg[p] += coeff * Ksk_c
__global__ __launch_bounds__(256)
void attn_kernel(const float* __restrict__ Qk, const float* __restrict__ K,
                 const float* __restrict__ V, const float* __restrict__ Ksk,
                 const int* __restrict__ e_row, const float* __restrict__ e_attr,
                 const int* __restrict__ edge_perm, const int* __restrict__ col_start,
                 const int* __restrict__ patch_start, const float* __restrict__ dinv,
                 float* __restrict__ num, float* __restrict__ Kagg) {
    __shared__ float Qs[TJ][65];
    __shared__ float Ks_[TI][65];
    __shared__ float Vs[TI][65];
    __shared__ float dots[TJ][TI];
    __shared__ float accN[TJ][65];
    __shared__ float coef[TJ];
    __shared__ int   trow[TJ];
    __shared__ float Ksc[64];
    int c = blockIdx.x, t = threadIdx.x;
    int e0 = col_start[c], e1 = col_start[c + 1];
    int nt = e1 - e0 + 1;
    int i0 = patch_start[c], i1 = patch_start[c + 1];
    float dc = dinv[c];
    if (t < 64) Ksc[t] = Ksk[(size_t)c * 64 + t];

    for (int jc = 0; jc < nt; jc += TJ) {
        int mj = min(TJ, nt - jc);
        __syncthreads();   // protect trow/coef/accN from previous chunk's readers
        if (t < mj) {
            int j = jc + t; int p; float cf;
            if (j == 0) { p = c; cf = 1.f; }
            else { int e = edge_perm[e0 + j - 1]; p = e_row[e]; cf = dinv[p] * e_attr[e] * dc; }
            trow[t] = p; coef[t] = cf;
        }
        __syncthreads();
        for (int idx = t; idx < mj * 64; idx += 256) {
            int j = idx >> 6, d = idx & 63;
            Qs[j][d] = Qk[(size_t)trow[j] * 64 + d];
            accN[j][d] = 0.f;
        }
        __syncthreads();
        for (int ic = i0; ic < i1; ic += TI) {
            int ni = min(TI, i1 - ic);
            for (int idx = t; idx < ni * 16; idx += 256) {
                int i = idx >> 4, q = idx & 15;
                float4 kv = ((const float4*)(K + (size_t)(ic + i) * 64))[q];
                float4 vv = ((const float4*)(V + (size_t)(ic + i) * 64))[q];
                float* kd = &Ks_[i][q * 4];
                kd[0] = fmaxf(kv.x, 0.f); kd[1] = fmaxf(kv.y, 0.f);
                kd[2] = fmaxf(kv.z, 0.f); kd[3] = fmaxf(kv.w, 0.f);
                float* vd = &Vs[i][q * 4];
                vd[0] = vv.x; vd[1] = vv.y; vd[2] = vv.z; vd[3] = vv.w;
            }
            __syncthreads();
            // dots[j][i] = Qs[j] · Ks[i]
            for (int idx = t; idx < mj * TI; idx += 256) {
                int j = idx >> 5, i = idx & (TI - 1);
                if (i < ni) {
                    float s = 0.f;
#pragma unroll
                    for (int d = 0; d < 64; ++d) s = fmaf(Qs[j][d], Ks_[i][d], s);
                    dots[j][i] = s;
                }
            }
            __syncthreads();
            // accN[j] += dots[j][:] @ Vs
            {
                int j = t >> 4, d0 = (t & 15) * 4;
                if (j < mj) {
                    float a0 = accN[j][d0],   a1 = accN[j][d0+1];
                    float a2 = accN[j][d0+2], a3 = accN[j][d0+3];
                    for (int i = 0; i < ni; ++i) {
                        float dv = dots[j][i];
                        a0 = fmaf(dv, Vs[i][d0],   a0);
                        a1 = fmaf(dv, Vs[i][d0+1], a1);
                        a2 = fmaf(dv, Vs[i][d0+2], a2);
                        a3 = fmaf(dv, Vs[i][d0+3], a3);
                    }
                    accN[j][d0] = a0; accN[j][d0+1] = a1;
                    accN[j][d0+2] = a2; accN[j][d0+3] = a3;
                }
            }
            __syncthreads();
        }
        for (int idx = t; idx < mj * 64; idx += 256) {
            int j = idx >> 6, d = idx & 63;
            float cf = coef[j];
            atomicAdd(&num[(size_t)trow[j] * 64 + d],  cf * accN[j][d]);
            atomicAdd(&Kagg[(size_t)trow[j] * 64 + d], cf * Ksc[d]);
        }
    }
}

// ---------------- readout + softmax pool + classifier (fused) ----------------

__global__ __launch_bounds__(64)
void final_kernel(const float* __restrict__ num, const float* __restrict__ Qk,
                  const float* __restrict__ Kagg, const float* __restrict__ seed,
                  const float* __restrict__ Wc1, const float* __restrict__ bc1,
                  const float* __restrict__ Wc2, const float* __restrict__ bc2,
                  float* __restrict__ logits) {
    __shared__ float s_out[32][65];
    __shared__ float s_rd[32], s_sc[32], s_pool[64], s_c1[32], s_seed[64];
    int b = blockIdx.x, t = threadIdx.x;
    s_seed[t] = seed[t];
    if (t < 32) {
        int p = b * 32 + t;
        float den = 0.f;
        for (int d = 0; d < 64; ++d)
            den = fmaf(Qk[(size_t)p*64+d], Kagg[(size_t)p*64+d], den);
        s_rd[t] = 1.f / (den + EPSF);
    }
    __syncthreads();
    for (int p = 0; p < 32; ++p)
        s_out[p][t] = num[(size_t)(b*32+p)*64 + t] * s_rd[p];
    __syncthreads();
    if (t < 32) {
        float sc = 0.f;
        for (int d = 0; d < 64; ++d) sc = fmaf(s_out[t][d], s_seed[d], sc);
        s_sc[t] = sc * 0.125f;
    }
    __syncthreads();
    if (t == 0) {
        float mx = -1e30f;
        for (int p = 0; p < 32; ++p) mx = fmaxf(mx, s_sc[p]);
        float sm = 0.f;
        for (int p = 0; p < 32; ++p) { float e = expf(s_sc[p] - mx); s_sc[p] = e; sm += e; }
        float inv = 1.f / sm;
        for (int p = 0; p < 32; ++p) s_sc[p] *= inv;
    }
    __syncthreads();
    {
        float pa = 0.f;
        for (int p = 0; p < 32; ++p) pa = fmaf(s_sc[p], s_out[p][t], pa);
        s_pool[t] = pa;
    }
    __syncthreads();
    if (t < 32) {
        float a = bc1[t];
        for (int d = 0; d < 64; ++d) a = fmaf(s_pool[d], Wc1[d*32+t], a);
        s_c1[t] = fmaxf(a, 0.f);
    }
    __syncthreads();
    if (t < 10) {
        float a = bc2[t];
        for (int j = 0; j < 32; ++j) a = fmaf(s_c1[j], Wc2[j*10+t], a);
        logits[b*10+t] = a;
    }
}

// ---------------- launch ----------------

extern "C" void kernel_launch(void* const* d_in, const int* in_sizes, int n_in,
                              void* d_out, int out_size, void* d_ws, size_t ws_size,
                              hipStream_t stream) {
    const float* x      = (const float*)d_in[0];
    const int*   mapper = (const int*)d_in[1];
    const int*   batch  = (const int*)d_in[2];
    const int*   e_row  = (const int*)d_in[3];
    const int*   e_col  = (const int*)d_in[4];
    const float* e_attr = (const float*)d_in[5];
    const float* Wt1 = (const float*)d_in[6],  *bt1 = (const float*)d_in[7];
    const float* Wt2 = (const float*)d_in[8],  *bt2 = (const float*)d_in[9];
    const float* Wpre1 = (const float*)d_in[10], *bpre1 = (const float*)d_in[11];
    const float* Wpre2 = (const float*)d_in[12], *bpre2 = (const float*)d_in[13];
    const float* Wpost1 = (const float*)d_in[14], *bpost1 = (const float*)d_in[15];
    const float* Wpost2 = (const float*)d_in[16], *bpost2 = (const float*)d_in[17];
    const float* Wk = (const float*)d_in[18], *bk = (const float*)d_in[19];
    const float* Wv = (const float*)d_in[20], *bv = (const float*)d_in[21];
    const float* seed = (const float*)d_in[22];
    const float* Wc1 = (const float*)d_in[23], *bc1 = (const float*)d_in[24];
    const float* Wc2 = (const float*)d_in[25], *bc2 = (const float*)d_in[26];
    float* logits = (float*)d_out;

    const size_t NF = (size_t)NND * 64;
    float* ws = (float*)d_ws;
    float* A   = ws;            // h
    float* Qn  = ws + NF;       // node-level Q
    float* Kb  = ws + 2 * NF;   // K
    float* Vb  = ws + 3 * NF;   // V
    float* numb   = ws + 4 * NF;              // [PP*64] (zeroed)
    float* Kagg   = numb + PP * 64;           // [PP*64] (zeroed)
    float* Qs_raw = Kagg + PP * 64;
    float* Qkbuf  = Qs_raw + PP * 64;
    float* Kskbuf = Qkbuf + PP * 64;
    float* deg    = Kskbuf + PP * 64;         // (zeroed)
    int*   colcnt = (int*)(deg + PP);         // (zeroed)
    int*   colfill= colcnt + PP;              // (zeroed)
    float* dinv   = (float*)(colfill + PP);
    int* patch_start = (int*)(dinv + PP);     // [PP+1]
    int* col_start   = patch_start + PP + 1;  // [PP+1]
    int* edge_perm   = col_start + PP + 1;    // [EE]

    hipMemsetAsync(numb, 0, 2 * PP * 64 * sizeof(float), stream);
    hipMemsetAsync(deg, 0, 3 * PP * sizeof(int), stream);

    patch_bounds_kernel<<<NND / 256, 256, 0, stream>>>(batch, patch_start);
    edge_hist_kernel<<<EE / 256, 256, 0, stream>>>(e_row, e_col, e_attr, deg, colcnt);
    scan_dinv_kernel<<<1, PP, 0, stream>>>(colcnt, col_start, deg, dinv);
    edge_scatter_kernel<<<EE / 256, 256, 0, stream>>>(e_col, col_start, colfill, edge_perm);

    // h = relu(relu(x@Wt1+bt1)@Wt2+bt2)
    mlp2_kernel<true, false, true><<<NND / 128, 128, 0, stream>>>(
        x, nullptr, Wt1, bt1, Wt2, bt2, A);
    // hs = h[mapper]; K, V, Qnode in one pass
    qkv_kernel<<<NND / 128, 128, 0, stream>>>(
        A, mapper, Wk, bk, Wv, bv, Wpre1, bpre1, Wpre2, bpre2, Kb, Vb, Qn);
    // per-patch: Qs_raw = Σ Qn ; Ksk = relu(mean K)
    patch_reduce_kernel<<<PP, 256, 0, stream>>>(Qn, Kb, patch_start, Qs_raw, Kskbuf);
    // Qk = relu(post-deepset(Qs_raw))
    mlp2_kernel<true, false, true><<<PP / 128, 128, 0, stream>>>(
        Qs_raw, nullptr, Wpost1, bpost1, Wpost2, bpost2, Qkbuf);
    // kernelized attention, col-grouped, atomically accumulating num & Kagg
    attn_kernel<<<PP, 256, 0, stream>>>(Qkbuf, Kb, Vb, Kskbuf, e_row, e_attr, edge_perm,
                                        col_start, patch_start, dinv, numb, Kagg);
    // readout + pool + classifier
    final_kernel<<<32, 64, 0, stream>>>(numb, Qkbuf, Kagg, seed, Wc1, bc1, Wc2, bc2, logits);
}

// Round 6
// 214.946 us; speedup vs baseline: 1.5006x; 1.5006x over previous
//
#include <hip/hip_runtime.h>
#include <cstddef>

#define NND  65536
#define PP   1024
#define EE   16384
#define TJA  48
#define TI   32
#define EPSF 1e-6f

typedef unsigned int   u32;
typedef unsigned short u16;
typedef __attribute__((ext_vector_type(8))) short bf16x8;
typedef __attribute__((ext_vector_type(4))) float f32x4;

__device__ __forceinline__ u16 f2bf(float f) {
    u32 u = __float_as_uint(f);
    u += 0x7fffu + ((u >> 16) & 1u);
    return (u16)(u >> 16);
}
__device__ __forceinline__ float bflo(u32 u) { return __uint_as_float(u << 16); }
__device__ __forceinline__ float bfhi(u32 u) { return __uint_as_float(u & 0xffff0000u); }
__device__ __forceinline__ float bf1(u16 v)  { return __uint_as_float(((u32)v) << 16); }

// ---------------- setup kernels ----------------

__global__ void patch_bounds_kernel(const int* __restrict__ batch, int* __restrict__ start) {
    int i = blockIdx.x * blockDim.x + threadIdx.x;
    if (i >= NND) return;
    int b  = batch[i];
    int bp = (i == 0) ? -1 : batch[i - 1];
    for (int p = bp + 1; p <= b; ++p) start[p] = i;
    if (i == NND - 1) {
        for (int p = b + 1; p <= PP; ++p) start[p] = NND;
    }
}

__global__ void edge_hist_kernel(const int* __restrict__ row, const int* __restrict__ col,
                                 const float* __restrict__ attr,
                                 float* __restrict__ deg, int* __restrict__ colcnt) {
    int e = blockIdx.x * blockDim.x + threadIdx.x;
    if (e >= EE) return;
    atomicAdd(&deg[row[e]], attr[e]);
    atomicAdd(&colcnt[col[e]], 1);
}

__global__ void scan_dinv_kernel(const int* __restrict__ colcnt, int* __restrict__ col_start,
                                 const float* __restrict__ deg, float* __restrict__ dinv) {
    __shared__ int s[PP];
    int t = threadIdx.x;
    s[t] = colcnt[t];
    float dg = deg[t];
    dinv[t] = (dg > 0.f) ? rsqrtf(fmaxf(dg, EPSF)) : 0.f;
    __syncthreads();
    for (int off = 1; off < PP; off <<= 1) {
        int v = (t >= off) ? s[t - off] : 0;
        __syncthreads();
        s[t] += v;
        __syncthreads();
    }
    col_start[t + 1] = s[t];
    if (t == 0) col_start[0] = 0;
}

__global__ void edge_scatter_kernel(const int* __restrict__ col, const int* __restrict__ col_start,
                                    int* __restrict__ colfill, int* __restrict__ edge_perm) {
    int e = blockIdx.x * blockDim.x + threadIdx.x;
    if (e >= EE) return;
    int c = col[e];
    int pos = col_start[c] + atomicAdd(&colfill[c], 1);
    edge_perm[pos] = e;
}

// ---------------- weight packing (fp32 [64][64] -> bf16 B-fragment layout) ----------------
// packed[((kk*4+nt)*64 + lane)*8 + j] = bf16( W[32*kk + 8*(lane>>4) + j][16*nt + (lane&15)] )
__global__ __launch_bounds__(256)
void pack_w_kernel(const float* W0, const float* W1, const float* W2, const float* W3,
                   const float* W4, const float* W5, const float* W6, const float* W7,
                   u16* __restrict__ out) {
    const float* Ws[8] = {W0, W1, W2, W3, W4, W5, W6, W7};
    const float* W = Ws[blockIdx.x];
    u16* dst = out + (size_t)blockIdx.x * 4096;
    int t = threadIdx.x;
    for (int idx = t; idx < 512; idx += 256) {   // (frag, lane) pairs
        int f = idx >> 6, l = idx & 63;
        int kk = f >> 2, nt = f & 3;
        int g = l >> 4, m = l & 15;
#pragma unroll
        for (int j = 0; j < 8; ++j) {
            int k = kk * 32 + g * 8 + j;
            int n = nt * 16 + m;
            dst[idx * 8 + j] = f2bf(W[k * 64 + n]);
        }
    }
}

// ---------------- MFMA GEMM building blocks ----------------
// LDS tile: 64 rows x 128 bytes (64 bf16), XOR-swizzled: byte ^= ((row&7)<<4).
// Wave w owns rows 16w..16w+15 exclusively -> no __syncthreads anywhere.

__device__ __forceinline__ void stage_f32(const float* __restrict__ in, u16* s, int row0, int t) {
    int r = t >> 2, c = t & 3;                       // 16 floats per thread
    const float4* src = (const float4*)(in + (size_t)(row0 + r) * 64 + c * 16);
    char* sb = (char*)s + r * 128;
    int swz = (r & 7) << 4;
#pragma unroll
    for (int q4 = 0; q4 < 4; ++q4) {
        float4 v = src[q4];
        u32 p0 = (u32)f2bf(v.x) | ((u32)f2bf(v.y) << 16);
        u32 p1 = (u32)f2bf(v.z) | ((u32)f2bf(v.w) << 16);
        int pc = c * 8 + q4 * 2;                      // bf16-pair index
        *(u32*)(sb + ((pc * 4) ^ swz))       = p0;
        *(u32*)(sb + (((pc + 1) * 4) ^ swz)) = p1;
    }
}

__device__ __forceinline__ void stage_bf16_gather(const u16* __restrict__ h,
                                                  const int* __restrict__ gmap,
                                                  u16* s, int row0, int t) {
    int r = t >> 2, c = t & 3;
    int sr = gmap[row0 + r];
    const uint4* src = (const uint4*)(h + (size_t)sr * 64) + c * 2;
    uint4 a = src[0], b = src[1];
    char* sb = (char*)s + r * 128;
    int swz = (r & 7) << 4;
    *(uint4*)(sb + ((c * 32) ^ swz))      = a;
    *(uint4*)(sb + ((c * 32 + 16) ^ swz)) = b;
}

template <bool RELU>
__device__ __forceinline__ void gemm_layer(const u16* src, u16* dst,
                                           const u16* __restrict__ Wp,
                                           const float* __restrict__ bias,
                                           int wv, int lane) {
    int g = lane >> 4, m = lane & 15;
    int arow = wv * 16 + m;
    const char* sb = (const char*)src + arow * 128;
    int aswz = (arow & 7) << 4;
    bf16x8 a0 = *(const bf16x8*)(sb + ((g * 16) ^ aswz));
    bf16x8 a1 = *(const bf16x8*)(sb + ((64 + g * 16) ^ aswz));
    const bf16x8* wp = (const bf16x8*)Wp;
#pragma unroll
    for (int ntile = 0; ntile < 4; ++ntile) {
        float bv = bias[ntile * 16 + m];
        f32x4 acc = {bv, bv, bv, bv};
        acc = __builtin_amdgcn_mfma_f32_16x16x32_bf16(a0, wp[(0 * 4 + ntile) * 64 + lane], acc, 0, 0, 0);
        acc = __builtin_amdgcn_mfma_f32_16x16x32_bf16(a1, wp[(1 * 4 + ntile) * 64 + lane], acc, 0, 0, 0);
        int col = ntile * 16 + m;
#pragma unroll
        for (int rg = 0; rg < 4; ++rg) {
            float v = acc[rg];
            if (RELU) v = fmaxf(v, 0.f);
            int rr = wv * 16 + g * 4 + rg;            // C layout: row=(lane>>4)*4+reg, col=lane&15
            *(u16*)((char*)dst + rr * 128 + ((2 * col) ^ ((rr & 7) << 4))) = f2bf(v);
        }
    }
}

template <bool RELU>
__device__ __forceinline__ void gemm_layer_f32out(const u16* src, float* __restrict__ out,
                                                  const u16* __restrict__ Wp,
                                                  const float* __restrict__ bias,
                                                  int row0, int wv, int lane) {
    int g = lane >> 4, m = lane & 15;
    int arow = wv * 16 + m;
    const char* sb = (const char*)src + arow * 128;
    int aswz = (arow & 7) << 4;
    bf16x8 a0 = *(const bf16x8*)(sb + ((g * 16) ^ aswz));
    bf16x8 a1 = *(const bf16x8*)(sb + ((64 + g * 16) ^ aswz));
    const bf16x8* wp = (const bf16x8*)Wp;
#pragma unroll
    for (int ntile = 0; ntile < 4; ++ntile) {
        float bv = bias[ntile * 16 + m];
        f32x4 acc = {bv, bv, bv, bv};
        acc = __builtin_amdgcn_mfma_f32_16x16x32_bf16(a0, wp[(0 * 4 + ntile) * 64 + lane], acc, 0, 0, 0);
        acc = __builtin_amdgcn_mfma_f32_16x16x32_bf16(a1, wp[(1 * 4 + ntile) * 64 + lane], acc, 0, 0, 0);
        int col = ntile * 16 + m;
#pragma unroll
        for (int rg = 0; rg < 4; ++rg) {
            float v = acc[rg];
            if (RELU) v = fmaxf(v, 0.f);
            out[(size_t)(row0 + wv * 16 + g * 4 + rg) * 64 + col] = v;
        }
    }
}

__device__ __forceinline__ void copy_out_bf16(const u16* s, u16* __restrict__ g, int row0, int t) {
    int r = t >> 2, c = t & 3;
    const char* sb = (const char*)s + r * 128;
    int swz = (r & 7) << 4;
    uint4 a = *(const uint4*)(sb + ((c * 32) ^ swz));
    uint4 b = *(const uint4*)(sb + ((c * 32 + 16) ^ swz));
    uint4* dst = (uint4*)(g + (size_t)(row0 + r) * 64) + c * 2;
    dst[0] = a; dst[1] = b;
}

// ---------------- fused 2-layer MLP (input transform / post-deepset) ----------------
template <bool OUT_BF16>
__global__ __launch_bounds__(256)
void mfma_mlp2_kernel(const float* __restrict__ in,
                      const u16* __restrict__ Wp1, const float* __restrict__ b1,
                      const u16* __restrict__ Wp2, const float* __restrict__ b2,
                      void* __restrict__ out) {
    __shared__ __align__(16) u16 xs[4096];
    __shared__ __align__(16) u16 ys[4096];
    int t = threadIdx.x, lane = t & 63, wv = t >> 6;
    int row0 = blockIdx.x * 64;
    stage_f32(in, xs, row0, t);
    gemm_layer<true>(xs, ys, Wp1, b1, wv, lane);
    if (OUT_BF16) {
        gemm_layer<true>(ys, xs, Wp2, b2, wv, lane);
        copy_out_bf16(xs, (u16*)out, row0, t);
    } else {
        gemm_layer_f32out<true>(ys, (float*)out, Wp2, b2, row0, wv, lane);
    }
}

// ---------------- fused K / V / pre-deepset (4 layers off one gathered tile) ----------------
__global__ __launch_bounds__(256)
void qkv_mfma_kernel(const u16* __restrict__ h, const int* __restrict__ gmap,
                     const u16* __restrict__ Wpk, const float* __restrict__ bk,
                     const u16* __restrict__ Wpv, const float* __restrict__ bv,
                     const u16* __restrict__ Wp1, const float* __restrict__ bp1,
                     const u16* __restrict__ Wp2, const float* __restrict__ bp2,
                     u16* __restrict__ Kout, u16* __restrict__ Vout, u16* __restrict__ Qout) {
    __shared__ __align__(16) u16 xs[4096];
    __shared__ __align__(16) u16 ys[4096];
    int t = threadIdx.x, lane = t & 63, wv = t >> 6;
    int row0 = blockIdx.x * 64;
    stage_bf16_gather(h, gmap, xs, row0, t);
    gemm_layer<false>(xs, ys, Wpk, bk, wv, lane);    // K = hs@Wk+bk
    copy_out_bf16(ys, Kout, row0, t);
    gemm_layer<false>(xs, ys, Wpv, bv, wv, lane);    // V = hs@Wv+bv
    copy_out_bf16(ys, Vout, row0, t);
    gemm_layer<true>(xs, ys, Wp1, bp1, wv, lane);    // t1 = relu(hs@Wpre1+bpre1)
    gemm_layer<false>(ys, xs, Wp2, bp2, wv, lane);   // Qn = t1@Wpre2+bpre2
    copy_out_bf16(xs, Qout, row0, t);
}

// ---------------- per-patch reductions (bf16 in, fp32 out) ----------------
__global__ __launch_bounds__(256)
void patch_reduce_kernel(const u16* __restrict__ Qn, const u16* __restrict__ K,
                         const int* __restrict__ start,
                         float* __restrict__ Qs_raw, float* __restrict__ Ksk) {
    __shared__ float qred[4][64], kred[4][64];
    int p = blockIdx.x, t = threadIdx.x;
    int d = t & 63, s = t >> 6;
    int i0 = start[p], i1 = start[p + 1];
    float qa = 0.f, ka = 0.f;
    for (int i = i0 + s; i < i1; i += 4) {
        qa += bf1(Qn[(size_t)i * 64 + d]);
        ka += bf1(K[(size_t)i * 64 + d]);
    }
    qred[s][d] = qa; kred[s][d] = ka;
    __syncthreads();
    if (s == 0) {
        float q = qred[0][d] + qred[1][d] + qred[2][d] + qred[3][d];
        float k = kred[0][d] + kred[1][d] + kred[2][d] + kred[3][d];
        Qs_raw[(size_t)p * 64 + d] = q;
        int cnt = i1 - i0;
        Ksk[(size_t)p * 64 + d] = fmaxf(k / (float)max(cnt, 1), 0.f);
    }
}

// ---------------- col-grouped kernelized attention ----------------
__global__ __launch_bounds__(256)
void attn_kernel(const float* __restrict__ Qk, const u16* __restrict__ K,
                 const u16* __restrict__ V, const float* __restrict__ Ksk,
                 const int* __restrict__ e_row, const float* __restrict__ e_attr,
                 const int* __restrict__ edge_perm, const int* __restrict__ col_start,
                 const int* __restrict__ patch_start, const float* __restrict__ dinv,
                 float* __restrict__ num, float* __restrict__ Kagg) {
    __shared__ float Qs[TJA][65];
    __shared__ float accN[TJA][65];
    __shared__ float Ks_[TI][65];
    __shared__ float Vs[TI][65];
    __shared__ float dots[TJA][TI];
    __shared__ float coef[TJA];
    __shared__ int   trow[TJA];
    __shared__ float Ksc[64];
    int c = blockIdx.x, t = threadIdx.x;
    int e0 = col_start[c], e1 = col_start[c + 1];
    int ntgt = e1 - e0 + 1;
    int i0 = patch_start[c], i1 = patch_start[c + 1];
    float dc = dinv[c];
    if (t < 64) Ksc[t] = Ksk[(size_t)c * 64 + t];

    for (int jc = 0; jc < ntgt; jc += TJA) {
        int mj = min(TJA, ntgt - jc);
        __syncthreads();
        if (t < mj) {
            int j = jc + t; int p; float cf;
            if (j == 0) { p = c; cf = 1.f; }
            else { int e = edge_perm[e0 + j - 1]; p = e_row[e]; cf = dinv[p] * e_attr[e] * dc; }
            trow[t] = p; coef[t] = cf;
        }
        __syncthreads();
        for (int idx = t; idx < mj * 64; idx += 256) {
            int j = idx >> 6, d = idx & 63;
            Qs[j][d] = Qk[(size_t)trow[j] * 64 + d];
            accN[j][d] = 0.f;
        }
        __syncthreads();
        for (int ic = i0; ic < i1; ic += TI) {
            int ni = min(TI, i1 - ic);
            for (int idx = t; idx < ni * 16; idx += 256) {
                int i = idx >> 4, q = idx & 15;
                uint2 kv = ((const uint2*)(K + (size_t)(ic + i) * 64))[q];
                uint2 vv = ((const uint2*)(V + (size_t)(ic + i) * 64))[q];
                float* kd = &Ks_[i][q * 4];
                kd[0] = fmaxf(bflo(kv.x), 0.f); kd[1] = fmaxf(bfhi(kv.x), 0.f);
                kd[2] = fmaxf(bflo(kv.y), 0.f); kd[3] = fmaxf(bfhi(kv.y), 0.f);
                float* vd = &Vs[i][q * 4];
                vd[0] = bflo(vv.x); vd[1] = bfhi(vv.x);
                vd[2] = bflo(vv.y); vd[3] = bfhi(vv.y);
            }
            __syncthreads();
            for (int idx = t; idx < mj * TI; idx += 256) {
                int j = idx >> 5, i = idx & (TI - 1);
                float s = 0.f;
#pragma unroll
                for (int d = 0; d < 64; ++d) s = fmaf(Qs[j][d], Ks_[i][d], s);
                dots[j][i] = s;                   // i>=ni lanes write garbage, never read
            }
            __syncthreads();
            {
                int d0 = (t & 15) * 4;
                for (int j = t >> 4; j < mj; j += 16) {
                    float a0 = accN[j][d0],     a1 = accN[j][d0 + 1];
                    float a2 = accN[j][d0 + 2], a3 = accN[j][d0 + 3];
                    for (int i = 0; i < ni; ++i) {
                        float dv = dots[j][i];
                        a0 = fmaf(dv, Vs[i][d0],     a0);
                        a1 = fmaf(dv, Vs[i][d0 + 1], a1);
                        a2 = fmaf(dv, Vs[i][d0 + 2], a2);
                        a3 = fmaf(dv, Vs[i][d0 + 3], a3);
                    }
                    accN[j][d0] = a0; accN[j][d0 + 1] = a1;
                    accN[j][d0 + 2] = a2; accN[j][d0 + 3] = a3;
                }
            }
            __syncthreads();
        }
        for (int idx = t; idx < mj * 64; idx += 256) {
            int j = idx >> 6, d = idx & 63;
            float cf = coef[j];
            atomicAdd(&num[(size_t)trow[j] * 64 + d],  cf * accN[j][d]);
            atomicAdd(&Kagg[(size_t)trow[j] * 64 + d], cf * Ksc[d]);
        }
    }
}

// ---------------- readout + softmax pool + classifier ----------------
__global__ __launch_bounds__(64)
void final_kernel(const float* __restrict__ num, const float* __restrict__ Qk,
                  const float* __restrict__ Kagg, const float* __restrict__ seed,
                  const float* __restrict__ Wc1, const float* __restrict__ bc1,
                  const float* __restrict__ Wc2, const float* __restrict__ bc2,
                  float* __restrict__ logits) {
    __shared__ float s_out[32][65];
    __shared__ float s_rd[32], s_sc[32], s_pool[64], s_c1[32], s_seed[64];
    int b = blockIdx.x, t = threadIdx.x;
    s_seed[t] = seed[t];
    if (t < 32) {
        int p = b * 32 + t;
        float den = 0.f;
        for (int d = 0; d < 64; ++d)
            den = fmaf(Qk[(size_t)p * 64 + d], Kagg[(size_t)p * 64 + d], den);
        s_rd[t] = 1.f / (den + EPSF);
    }
    __syncthreads();
    for (int p = 0; p < 32; ++p)
        s_out[p][t] = num[(size_t)(b * 32 + p) * 64 + t] * s_rd[p];
    __syncthreads();
    if (t < 32) {
        float sc = 0.f;
        for (int d = 0; d < 64; ++d) sc = fmaf(s_out[t][d], s_seed[d], sc);
        s_sc[t] = sc * 0.125f;
    }
    __syncthreads();
    if (t == 0) {
        float mx = -1e30f;
        for (int p = 0; p < 32; ++p) mx = fmaxf(mx, s_sc[p]);
        float sm = 0.f;
        for (int p = 0; p < 32; ++p) { float e = expf(s_sc[p] - mx); s_sc[p] = e; sm += e; }
        float inv = 1.f / sm;
        for (int p = 0; p < 32; ++p) s_sc[p] *= inv;
    }
    __syncthreads();
    {
        float pa = 0.f;
        for (int p = 0; p < 32; ++p) pa = fmaf(s_sc[p], s_out[p][t], pa);
        s_pool[t] = pa;
    }
    __syncthreads();
    if (t < 32) {
        float a = bc1[t];
        for (int d = 0; d < 64; ++d) a = fmaf(s_pool[d], Wc1[d * 32 + t], a);
        s_c1[t] = fmaxf(a, 0.f);
    }
    __syncthreads();
    if (t < 10) {
        float a = bc2[t];
        for (int j = 0; j < 32; ++j) a = fmaf(s_c1[j], Wc2[j * 10 + t], a);
        logits[b * 10 + t] = a;
    }
}

// ---------------- launch ----------------

extern "C" void kernel_launch(void* const* d_in, const int* in_sizes, int n_in,
                              void* d_out, int out_size, void* d_ws, size_t ws_size,
                              hipStream_t stream) {
    const float* x      = (const float*)d_in[0];
    const int*   mapper = (const int*)d_in[1];
    const int*   batch  = (const int*)d_in[2];
    const int*   e_row  = (const int*)d_in[3];
    const int*   e_col  = (const int*)d_in[4];
    const float* e_attr = (const float*)d_in[5];
    const float* Wt1 = (const float*)d_in[6],  *bt1 = (const float*)d_in[7];
    const float* Wt2 = (const float*)d_in[8],  *bt2 = (const float*)d_in[9];
    const float* Wpre1 = (const float*)d_in[10], *bpre1 = (const float*)d_in[11];
    const float* Wpre2 = (const float*)d_in[12], *bpre2 = (const float*)d_in[13];
    const float* Wpost1 = (const float*)d_in[14], *bpost1 = (const float*)d_in[15];
    const float* Wpost2 = (const float*)d_in[16], *bpost2 = (const float*)d_in[17];
    const float* Wk = (const float*)d_in[18], *bk = (const float*)d_in[19];
    const float* Wv = (const float*)d_in[20], *bv = (const float*)d_in[21];
    const float* seed = (const float*)d_in[22];
    const float* Wc1 = (const float*)d_in[23], *bc1 = (const float*)d_in[24];
    const float* Wc2 = (const float*)d_in[25], *bc2 = (const float*)d_in[26];
    float* logits = (float*)d_out;

    char* w = (char*)d_ws;
    const size_t NB2 = (size_t)NND * 64 * 2;   // bf16 node buffer bytes
    u16* hb  = (u16*)w;             w += NB2;
    u16* Kb  = (u16*)w;             w += NB2;
    u16* Vb  = (u16*)w;             w += NB2;
    u16* Qnb = (u16*)w;             w += NB2;
    u16* Wp  = (u16*)w;             w += 8 * 4096 * 2;
    float* numb   = (float*)w;      w += PP * 64 * 4;
    float* Kagg   = (float*)w;      w += PP * 64 * 4;
    float* Qs_raw = (float*)w;      w += PP * 64 * 4;
    float* Qkb    = (float*)w;      w += PP * 64 * 4;
    float* Kskb   = (float*)w;      w += PP * 64 * 4;
    float* deg    = (float*)w;      w += PP * 4;
    int*   colcnt = (int*)w;        w += PP * 4;
    int*   colfill= (int*)w;        w += PP * 4;
    float* dinv   = (float*)w;      w += PP * 4;
    int* patch_start = (int*)w;     w += (PP + 1) * 4;
    int* col_start   = (int*)w;     w += (PP + 1) * 4;
    int* edge_perm   = (int*)w;     w += EE * 4;

    hipMemsetAsync(numb, 0, 2 * PP * 64 * sizeof(float), stream);
    hipMemsetAsync(deg, 0, 3 * PP * sizeof(int), stream);

    patch_bounds_kernel<<<NND / 256, 256, 0, stream>>>(batch, patch_start);
    edge_hist_kernel<<<EE / 256, 256, 0, stream>>>(e_row, e_col, e_attr, deg, colcnt);
    scan_dinv_kernel<<<1, PP, 0, stream>>>(colcnt, col_start, deg, dinv);
    edge_scatter_kernel<<<EE / 256, 256, 0, stream>>>(e_col, col_start, colfill, edge_perm);

    // pack weights: {t1,t2,k,v,pre1,pre2,post1,post2}
    pack_w_kernel<<<8, 256, 0, stream>>>(Wt1, Wt2, Wk, Wv, Wpre1, Wpre2, Wpost1, Wpost2, Wp);

    // h = relu(relu(x@Wt1+bt1)@Wt2+bt2)  -> bf16
    mfma_mlp2_kernel<true><<<NND / 64, 256, 0, stream>>>(
        x, Wp + 0 * 4096, bt1, Wp + 1 * 4096, bt2, hb);
    // gather hs = h[mapper]; K, V, Qn  -> bf16
    qkv_mfma_kernel<<<NND / 64, 256, 0, stream>>>(
        hb, mapper, Wp + 2 * 4096, bk, Wp + 3 * 4096, bv,
        Wp + 4 * 4096, bpre1, Wp + 5 * 4096, bpre2, Kb, Vb, Qnb);
    // per-patch: Qs_raw = sum Qn ; Ksk = relu(mean K)
    patch_reduce_kernel<<<PP, 256, 0, stream>>>(Qnb, Kb, patch_start, Qs_raw, Kskb);
    // Qk = relu(post-deepset(Qs_raw)) -> fp32
    mfma_mlp2_kernel<false><<<PP / 64, 256, 0, stream>>>(
        Qs_raw, Wp + 6 * 4096, bpost1, Wp + 7 * 4096, bpost2, Qkb);
    // kernelized attention over coarsened graph
    attn_kernel<<<PP, 256, 0, stream>>>(Qkb, Kb, Vb, Kskb, e_row, e_attr, edge_perm,
                                        col_start, patch_start, dinv, numb, Kagg);
    // readout + pool + classifier
    final_kernel<<<32, 64, 0, stream>>>(numb, Qkb, Kagg, seed, Wc1, bc1, Wc2, bc2, logits);
}

// Round 9
// 199.331 us; speedup vs baseline: 1.6181x; 1.0783x over previous
//
#include <hip/hip_runtime.h>
#include <cstddef>

#define NND  65536
#define PP   1024
#define EE   16384
#define CAP  88      // node chunk per attn block
#define TJ2  32      // target chunk per attn block
#define EPSF 1e-6f

typedef unsigned int   u32;
typedef unsigned short u16;
typedef __attribute__((ext_vector_type(8))) short bf16x8;
typedef __attribute__((ext_vector_type(4))) float f32x4;

__device__ __forceinline__ u16 f2bf(float f) {
    u32 u = __float_as_uint(f);
    u += 0x7fffu + ((u >> 16) & 1u);
    return (u16)(u >> 16);
}
__device__ __forceinline__ float bflo(u32 u) { return __uint_as_float(u << 16); }
__device__ __forceinline__ float bfhi(u32 u) { return __uint_as_float(u & 0xffff0000u); }
__device__ __forceinline__ float bf1(u16 v)  { return __uint_as_float(((u32)v) << 16); }
// relu on a packed pair of bf16: clear any half whose sign bit is set
__device__ __forceinline__ u32 relu2(u32 v) {
    u32 mask = ((v & 0x80008000u) >> 15) * 0xFFFFu;
    return v & ~mask;
}

// ---------------- setup kernels ----------------

__global__ void patch_bounds_kernel(const int* __restrict__ batch, int* __restrict__ start) {
    int i = blockIdx.x * blockDim.x + threadIdx.x;
    if (i >= NND) return;
    int b  = batch[i];
    int bp = (i == 0) ? -1 : batch[i - 1];
    for (int p = bp + 1; p <= b; ++p) start[p] = i;
    if (i == NND - 1) {
        for (int p = b + 1; p <= PP; ++p) start[p] = NND;
    }
}

__global__ void edge_hist_kernel(const int* __restrict__ row, const int* __restrict__ col,
                                 const float* __restrict__ attr,
                                 float* __restrict__ deg, int* __restrict__ colcnt) {
    int e = blockIdx.x * blockDim.x + threadIdx.x;
    if (e >= EE) return;
    atomicAdd(&deg[row[e]], attr[e]);
    atomicAdd(&colcnt[col[e]], 1);
}

__global__ void scan_dinv_kernel(const int* __restrict__ colcnt, int* __restrict__ col_start,
                                 const float* __restrict__ deg, float* __restrict__ dinv) {
    __shared__ int s[PP];
    int t = threadIdx.x;
    s[t] = colcnt[t];
    float dg = deg[t];
    dinv[t] = (dg > 0.f) ? rsqrtf(fmaxf(dg, EPSF)) : 0.f;
    __syncthreads();
    for (int off = 1; off < PP; off <<= 1) {
        int v = (t >= off) ? s[t - off] : 0;
        __syncthreads();
        s[t] += v;
        __syncthreads();
    }
    col_start[t + 1] = s[t];
    if (t == 0) col_start[0] = 0;
}

__global__ void edge_scatter_kernel(const int* __restrict__ col, const int* __restrict__ col_start,
                                    int* __restrict__ colfill, int* __restrict__ edge_perm) {
    int e = blockIdx.x * blockDim.x + threadIdx.x;
    if (e >= EE) return;
    int c = col[e];
    int pos = col_start[c] + atomicAdd(&colfill[c], 1);
    edge_perm[pos] = e;
}

// ---------------- weight packing (fp32 [64][64] -> bf16 B-fragment layout) ----------------
__global__ __launch_bounds__(256)
void pack_w_kernel(const float* W0, const float* W1, const float* W2, const float* W3,
                   const float* W4, const float* W5, const float* W6, const float* W7,
                   u16* __restrict__ out) {
    const float* Ws[8] = {W0, W1, W2, W3, W4, W5, W6, W7};
    const float* W = Ws[blockIdx.x];
    u16* dst = out + (size_t)blockIdx.x * 4096;
    int t = threadIdx.x;
    for (int idx = t; idx < 512; idx += 256) {
        int f = idx >> 6, l = idx & 63;
        int kk = f >> 2, nt = f & 3;
        int g = l >> 4, m = l & 15;
#pragma unroll
        for (int j = 0; j < 8; ++j) {
            int k = kk * 32 + g * 8 + j;
            int n = nt * 16 + m;
            dst[idx * 8 + j] = f2bf(W[k * 64 + n]);
        }
    }
}

// ---------------- MFMA GEMM building blocks ----------------
// LDS tile: 64 rows x 128 bytes, XOR-swizzled byte ^= ((row&7)<<4).
// Wave w owns rows 16w..16w+15 exclusively -> no __syncthreads.

__device__ __forceinline__ void stage_f32(const float* __restrict__ in, u16* s, int row0, int t) {
    int r = t >> 2, c = t & 3;
    const float4* src = (const float4*)(in + (size_t)(row0 + r) * 64 + c * 16);
    char* sb = (char*)s + r * 128;
    int swz = (r & 7) << 4;
#pragma unroll
    for (int q4 = 0; q4 < 4; ++q4) {
        float4 v = src[q4];
        u32 p0 = (u32)f2bf(v.x) | ((u32)f2bf(v.y) << 16);
        u32 p1 = (u32)f2bf(v.z) | ((u32)f2bf(v.w) << 16);
        int pc = c * 8 + q4 * 2;
        *(u32*)(sb + ((pc * 4) ^ swz))       = p0;
        *(u32*)(sb + (((pc + 1) * 4) ^ swz)) = p1;
    }
}

__device__ __forceinline__ void stage_bf16_gather(const u16* __restrict__ h,
                                                  const int* __restrict__ gmap,
                                                  u16* s, int row0, int t) {
    int r = t >> 2, c = t & 3;
    int sr = gmap[row0 + r];
    const uint4* src = (const uint4*)(h + (size_t)sr * 64) + c * 2;
    uint4 a = src[0], b = src[1];
    char* sb = (char*)s + r * 128;
    int swz = (r & 7) << 4;
    *(uint4*)(sb + ((c * 32) ^ swz))      = a;
    *(uint4*)(sb + ((c * 32 + 16) ^ swz)) = b;
}

template <bool RELU>
__device__ __forceinline__ void gemm_layer(const u16* src, u16* dst,
                                           const u16* __restrict__ Wp,
                                           const float* __restrict__ bias,
                                           int wv, int lane) {
    int g = lane >> 4, m = lane & 15;
    int arow = wv * 16 + m;
    const char* sb = (const char*)src + arow * 128;
    int aswz = (arow & 7) << 4;
    bf16x8 a0 = *(const bf16x8*)(sb + ((g * 16) ^ aswz));
    bf16x8 a1 = *(const bf16x8*)(sb + ((64 + g * 16) ^ aswz));
    const bf16x8* wp = (const bf16x8*)Wp;
#pragma unroll
    for (int ntile = 0; ntile < 4; ++ntile) {
        float bv = bias[ntile * 16 + m];
        f32x4 acc = {bv, bv, bv, bv};
        acc = __builtin_amdgcn_mfma_f32_16x16x32_bf16(a0, wp[(0 * 4 + ntile) * 64 + lane], acc, 0, 0, 0);
        acc = __builtin_amdgcn_mfma_f32_16x16x32_bf16(a1, wp[(1 * 4 + ntile) * 64 + lane], acc, 0, 0, 0);
        int col = ntile * 16 + m;
#pragma unroll
        for (int rg = 0; rg < 4; ++rg) {
            float v = acc[rg];
            if (RELU) v = fmaxf(v, 0.f);
            int rr = wv * 16 + g * 4 + rg;  // C layout: row=(lane>>4)*4+reg, col=lane&15
            *(u16*)((char*)dst + rr * 128 + ((2 * col) ^ ((rr & 7) << 4))) = f2bf(v);
        }
    }
}

__device__ __forceinline__ void copy_out_bf16(const u16* s, u16* __restrict__ g, int row0, int t) {
    int r = t >> 2, c = t & 3;
    const char* sb = (const char*)s + r * 128;
    int swz = (r & 7) << 4;
    uint4 a = *(const uint4*)(sb + ((c * 32) ^ swz));
    uint4 b = *(const uint4*)(sb + ((c * 32 + 16) ^ swz));
    uint4* dst = (uint4*)(g + (size_t)(row0 + r) * 64) + c * 2;
    dst[0] = a; dst[1] = b;
}

// ---------------- fused 2-layer MLP (input transform / post-deepset), bf16 out ----------------
__global__ __launch_bounds__(256)
void mfma_mlp2_kernel(const float* __restrict__ in,
                      const u16* __restrict__ Wp1, const float* __restrict__ b1,
                      const u16* __restrict__ Wp2, const float* __restrict__ b2,
                      u16* __restrict__ out) {
    __shared__ __align__(16) u16 xs[4096];
    __shared__ __align__(16) u16 ys[4096];
    int t = threadIdx.x, lane = t & 63, wv = t >> 6;
    int row0 = blockIdx.x * 64;
    stage_f32(in, xs, row0, t);
    gemm_layer<true>(xs, ys, Wp1, b1, wv, lane);
    gemm_layer<true>(ys, xs, Wp2, b2, wv, lane);
    copy_out_bf16(xs, out, row0, t);
}

// ---------------- fused K / V / pre-deepset (4 layers off one gathered tile) ----------------
__global__ __launch_bounds__(256)
void qkv_mfma_kernel(const u16* __restrict__ h, const int* __restrict__ gmap,
                     const u16* __restrict__ Wpk, const float* __restrict__ bk,
                     const u16* __restrict__ Wpv, const float* __restrict__ bv,
                     const u16* __restrict__ Wp1, const float* __restrict__ bp1,
                     const u16* __restrict__ Wp2, const float* __restrict__ bp2,
                     u16* __restrict__ Kout, u16* __restrict__ Vout, u16* __restrict__ Qout) {
    __shared__ __align__(16) u16 xs[4096];
    __shared__ __align__(16) u16 ys[4096];
    int t = threadIdx.x, lane = t & 63, wv = t >> 6;
    int row0 = blockIdx.x * 64;
    stage_bf16_gather(h, gmap, xs, row0, t);
    gemm_layer<false>(xs, ys, Wpk, bk, wv, lane);    // K = hs@Wk+bk
    copy_out_bf16(ys, Kout, row0, t);
    gemm_layer<false>(xs, ys, Wpv, bv, wv, lane);    // V = hs@Wv+bv
    copy_out_bf16(ys, Vout, row0, t);
    gemm_layer<true>(xs, ys, Wp1, bp1, wv, lane);    // t1 = relu(hs@Wpre1+bpre1)
    gemm_layer<false>(ys, xs, Wp2, bp2, wv, lane);   // Qn = t1@Wpre2+bpre2
    copy_out_bf16(xs, Qout, row0, t);
}

// ---------------- per-patch reductions (bf16 in, fp32 out), u32-vectorized ----------------
__global__ __launch_bounds__(256)
void patch_reduce_kernel(const u16* __restrict__ Qn, const u16* __restrict__ K,
                         const int* __restrict__ start,
                         float* __restrict__ Qs_raw, float* __restrict__ Ksk) {
    __shared__ float qred[8][64], kred[8][64];
    int p = blockIdx.x, t = threadIdx.x;
    int w = t & 31, s = t >> 5;          // 8 row-slices, 32 u32 words per row
    int i0 = start[p], i1 = start[p + 1];
    float qa0 = 0.f, qa1 = 0.f, ka0 = 0.f, ka1 = 0.f;
    for (int i = i0 + s; i < i1; i += 8) {
        u32 qv = ((const u32*)(Qn + (size_t)i * 64))[w];
        u32 kv = ((const u32*)(K  + (size_t)i * 64))[w];
        qa0 += bflo(qv); qa1 += bfhi(qv);
        ka0 += bflo(kv); ka1 += bfhi(kv);
    }
    qred[s][w * 2] = qa0; qred[s][w * 2 + 1] = qa1;
    kred[s][w * 2] = ka0; kred[s][w * 2 + 1] = ka1;
    __syncthreads();
    if (t < 64) {
        float q = 0.f, k = 0.f;
#pragma unroll
        for (int z = 0; z < 8; ++z) { q += qred[z][t]; k += kred[z][t]; }
        Qs_raw[(size_t)p * 64 + t] = q;
        int cnt = i1 - i0;
        Ksk[(size_t)p * 64 + t] = fmaxf(k / (float)max(cnt, 1), 0.f);
    }
}

// ---------------- col-grouped kernelized attention, wave-independent targets ----------------
// Per block c: stage relu(K), V (bf16, stride-66 rows: bank = node%32, conflict-free),
// Q target rows (bf16). Each wave owns targets {wv, wv+4, ...}:
//   phase1: lane=node, dot = Q_j . Kk_i from own LDS row -> dots[wv][i]
//   phase2: lane=dim,  acc_d += dots[i] (broadcast) * V[i][d], register accumulate
// No inter-wave syncs inside the target loop.
__global__ __launch_bounds__(256)
void attn2_kernel(const u16* __restrict__ Qkb, const u16* __restrict__ Kb,
                  const u16* __restrict__ Vb, const float* __restrict__ Kskb,
                  const int* __restrict__ e_row, const float* __restrict__ e_attr,
                  const int* __restrict__ edge_perm, const int* __restrict__ col_start,
                  const int* __restrict__ patch_start, const float* __restrict__ dinv,
                  float* __restrict__ num, float* __restrict__ Kagg) {
    __shared__ u16   Ks[CAP * 66];
    __shared__ u16   Vs[CAP * 66];
    __shared__ u16   Qs[TJ2 * 66];
    __shared__ float accS[TJ2 * 64];
    __shared__ float dots[4][CAP];
    __shared__ float coef[TJ2];
    __shared__ int   trow[TJ2];
    __shared__ float Ksc[64];
    int c = blockIdx.x, t = threadIdx.x, wv = t >> 6, lane = t & 63;
    int e0 = col_start[c], e1 = col_start[c + 1];
    int ntgt = e1 - e0 + 1;
    int i0 = patch_start[c], i1 = patch_start[c + 1];
    float dc = dinv[c];
    if (t < 64) Ksc[t] = Kskb[(size_t)c * 64 + t];

    for (int tc = 0; tc < ntgt; tc += TJ2) {
        int mj = min(TJ2, ntgt - tc);
        __syncthreads();                        // prev writeout readers done
        if (t < mj) {
            int j = tc + t; int p; float cf;
            if (j == 0) { p = c; cf = 1.f; }
            else { int e = edge_perm[e0 + j - 1]; p = e_row[e]; cf = dinv[p] * e_attr[e] * dc; }
            trow[t] = p; coef[t] = cf;
        }
        for (int idx = t; idx < mj * 64; idx += 256) accS[idx] = 0.f;
        __syncthreads();                        // meta visible
        // stage Q target rows (32 u32 per row)
        for (int idx = t; idx < mj * 32; idx += 256) {
            int j = idx >> 5, q = idx & 31;
            u32 v = ((const u32*)(Qkb + (size_t)trow[j] * 64))[q];
            *(u32*)&Qs[j * 66 + q * 2] = v;
        }
        for (int ic = i0; ic < i1; ic += CAP) {
            int nc = min(CAP, i1 - ic);
            __syncthreads();                    // prev chunk phase reads done
            // stage K (relu'd) and V: uint4 global loads, u32 LDS stores
            for (int idx = t; idx < nc * 8; idx += 256) {
                int i = idx >> 3, q = idx & 7;
                uint4 kv = *((const uint4*)(Kb + (size_t)(ic + i) * 64) + q);
                uint4 vv = *((const uint4*)(Vb + (size_t)(ic + i) * 64) + q);
                u32* kd = (u32*)&Ks[i * 66 + q * 8];
                kd[0] = relu2(kv.x); kd[1] = relu2(kv.y);
                kd[2] = relu2(kv.z); kd[3] = relu2(kv.w);
                u32* vd = (u32*)&Vs[i * 66 + q * 8];
                vd[0] = vv.x; vd[1] = vv.y; vd[2] = vv.z; vd[3] = vv.w;
            }
            __syncthreads();                    // staging (incl. Qs) visible
            for (int j = wv; j < mj; j += 4) {
                // phase1: lane = node
                for (int ib = 0; ib < nc; ib += 64) {
                    int i = ib + lane;
                    if (i < nc) {
                        float dot = 0.f;
                        const u32* kr = (const u32*)&Ks[i * 66];
                        const u32* qr = (const u32*)&Qs[j * 66];
#pragma unroll 8
                        for (int q = 0; q < 32; ++q) {
                            u32 kw = kr[q], qw = qr[q];
                            dot = fmaf(bflo(qw), bflo(kw), dot);
                            dot = fmaf(bfhi(qw), bfhi(kw), dot);
                        }
                        dots[wv][i] = dot;
                    }
                }
                // phase2: lane = dim (same-wave DS ops are ordered: dots visible)
                float out = 0.f;
#pragma unroll 4
                for (int i = 0; i < nc; ++i)
                    out = fmaf(dots[wv][i], bf1(Vs[i * 66 + lane]), out);
                accS[j * 64 + lane] += out;
            }
        }
        __syncthreads();                        // accS complete
        for (int idx = t; idx < mj * 64; idx += 256) {
            int j = idx >> 6, d = idx & 63;
            float cf = coef[j];
            atomicAdd(&num[(size_t)trow[j] * 64 + d],  cf * accS[j * 64 + d]);
            atomicAdd(&Kagg[(size_t)trow[j] * 64 + d], cf * Ksc[d]);
        }
    }
}

// ---------------- readout + softmax pool + classifier ----------------
__global__ __launch_bounds__(64)
void final_kernel(const float* __restrict__ num, const u16* __restrict__ Qk,
                  const float* __restrict__ Kagg, const float* __restrict__ seed,
                  const float* __restrict__ Wc1, const float* __restrict__ bc1,
                  const float* __restrict__ Wc2, const float* __restrict__ bc2,
                  float* __restrict__ logits) {
    __shared__ float s_out[32][65];
    __shared__ float s_rd[32], s_sc[32], s_pool[64], s_c1[32], s_seed[64];
    int b = blockIdx.x, t = threadIdx.x;
    s_seed[t] = seed[t];
    if (t < 32) {
        int p = b * 32 + t;
        float den = 0.f;
        for (int d = 0; d < 64; ++d)
            den = fmaf(bf1(Qk[(size_t)p * 64 + d]), Kagg[(size_t)p * 64 + d], den);
        s_rd[t] = 1.f / (den + EPSF);
    }
    __syncthreads();
    for (int p = 0; p < 32; ++p)
        s_out[p][t] = num[(size_t)(b * 32 + p) * 64 + t] * s_rd[p];
    __syncthreads();
    if (t < 32) {
        float sc = 0.f;
        for (int d = 0; d < 64; ++d) sc = fmaf(s_out[t][d], s_seed[d], sc);
        s_sc[t] = sc * 0.125f;
    }
    __syncthreads();
    if (t == 0) {
        float mx = -1e30f;
        for (int p = 0; p < 32; ++p) mx = fmaxf(mx, s_sc[p]);
        float sm = 0.f;
        for (int p = 0; p < 32; ++p) { float e = expf(s_sc[p] - mx); s_sc[p] = e; sm += e; }
        float inv = 1.f / sm;
        for (int p = 0; p < 32; ++p) s_sc[p] *= inv;
    }
    __syncthreads();
    {
        float pa = 0.f;
        for (int p = 0; p < 32; ++p) pa = fmaf(s_sc[p], s_out[p][t], pa);
        s_pool[t] = pa;
    }
    __syncthreads();
    if (t < 32) {
        float a = bc1[t];
        for (int d = 0; d < 64; ++d) a = fmaf(s_pool[d], Wc1[d * 32 + t], a);
        s_c1[t] = fmaxf(a, 0.f);
    }
    __syncthreads();
    if (t < 10) {
        float a = bc2[t];
        for (int j = 0; j < 32; ++j) a = fmaf(s_c1[j], Wc2[j * 10 + t], a);
        logits[b * 10 + t] = a;
    }
}

// ---------------- launch ----------------

extern "C" void kernel_launch(void* const* d_in, const int* in_sizes, int n_in,
                              void* d_out, int out_size, void* d_ws, size_t ws_size,
                              hipStream_t stream) {
    const float* x      = (const float*)d_in[0];
    const int*   mapper = (const int*)d_in[1];
    const int*   batch  = (const int*)d_in[2];
    const int*   e_row  = (const int*)d_in[3];
    const int*   e_col  = (const int*)d_in[4];
    const float* e_attr = (const float*)d_in[5];
    const float* Wt1 = (const float*)d_in[6],  *bt1 = (const float*)d_in[7];
    const float* Wt2 = (const float*)d_in[8],  *bt2 = (const float*)d_in[9];
    const float* Wpre1 = (const float*)d_in[10], *bpre1 = (const float*)d_in[11];
    const float* Wpre2 = (const float*)d_in[12], *bpre2 = (const float*)d_in[13];
    const float* Wpost1 = (const float*)d_in[14], *bpost1 = (const float*)d_in[15];
    const float* Wpost2 = (const float*)d_in[16], *bpost2 = (const float*)d_in[17];
    const float* Wk = (const float*)d_in[18], *bk = (const float*)d_in[19];
    const float* Wv = (const float*)d_in[20], *bv = (const float*)d_in[21];
    const float* seed = (const float*)d_in[22];
    const float* Wc1 = (const float*)d_in[23], *bc1 = (const float*)d_in[24];
    const float* Wc2 = (const float*)d_in[25], *bc2 = (const float*)d_in[26];
    float* logits = (float*)d_out;

    char* w = (char*)d_ws;
    const size_t NB2 = (size_t)NND * 64 * 2;   // bf16 node buffer bytes
    u16* hb  = (u16*)w;             w += NB2;
    u16* Kb  = (u16*)w;             w += NB2;
    u16* Vb  = (u16*)w;             w += NB2;
    u16* Qnb = (u16*)w;             w += NB2;
    u16* Wp  = (u16*)w;             w += 8 * 4096 * 2;
    u16* Qkb = (u16*)w;             w += PP * 64 * 2;   // bf16 patch-level Qk
    float* numb   = (float*)w;      w += PP * 64 * 4;
    float* Kagg   = (float*)w;      w += PP * 64 * 4;
    float* Qs_raw = (float*)w;      w += PP * 64 * 4;
    float* Kskb   = (float*)w;      w += PP * 64 * 4;
    float* deg    = (float*)w;      w += PP * 4;
    int*   colcnt = (int*)w;        w += PP * 4;
    int*   colfill= (int*)w;        w += PP * 4;
    float* dinv   = (float*)w;      w += PP * 4;
    int* patch_start = (int*)w;     w += (PP + 1) * 4;
    int* col_start   = (int*)w;     w += (PP + 1) * 4;
    int* edge_perm   = (int*)w;     w += EE * 4;

    hipMemsetAsync(numb, 0, 2 * PP * 64 * sizeof(float), stream);
    hipMemsetAsync(deg, 0, 3 * PP * sizeof(int), stream);

    patch_bounds_kernel<<<NND / 256, 256, 0, stream>>>(batch, patch_start);
    edge_hist_kernel<<<EE / 256, 256, 0, stream>>>(e_row, e_col, e_attr, deg, colcnt);
    scan_dinv_kernel<<<1, PP, 0, stream>>>(colcnt, col_start, deg, dinv);
    edge_scatter_kernel<<<EE / 256, 256, 0, stream>>>(e_col, col_start, colfill, edge_perm);

    // pack weights: {t1,t2,k,v,pre1,pre2,post1,post2}
    pack_w_kernel<<<8, 256, 0, stream>>>(Wt1, Wt2, Wk, Wv, Wpre1, Wpre2, Wpost1, Wpost2, Wp);

    // h = relu(relu(x@Wt1+bt1)@Wt2+bt2)  -> bf16
    mfma_mlp2_kernel<<<NND / 64, 256, 0, stream>>>(
        x, Wp + 0 * 4096, bt1, Wp + 1 * 4096, bt2, hb);
    // gather hs = h[mapper]; K, V, Qn  -> bf16
    qkv_mfma_kernel<<<NND / 64, 256, 0, stream>>>(
        hb, mapper, Wp + 2 * 4096, bk, Wp + 3 * 4096, bv,
        Wp + 4 * 4096, bpre1, Wp + 5 * 4096, bpre2, Kb, Vb, Qnb);
    // per-patch: Qs_raw = sum Qn ; Ksk = relu(mean K)
    patch_reduce_kernel<<<PP, 256, 0, stream>>>(Qnb, Kb, patch_start, Qs_raw, Kskb);
    // Qk = relu(post-deepset(Qs_raw)) -> bf16
    mfma_mlp2_kernel<<<PP / 64, 256, 0, stream>>>(
        Qs_raw, Wp + 6 * 4096, bpost1, Wp + 7 * 4096, bpost2, Qkb);
    // kernelized attention over coarsened graph
    attn2_kernel<<<PP, 256, 0, stream>>>(Qkb, Kb, Vb, Kskb, e_row, e_attr, edge_perm,
                                         col_start, patch_start, dinv, numb, Kagg);
    // readout + pool + classifier
    final_kernel<<<32, 64, 0, stream>>>(numb, Qkb, Kagg, seed, Wc1, bc1, Wc2, bc2, logits);
}